// Round 2
// baseline (5781.207 us; speedup 1.0000x reference)
//
#include <hip/hip_runtime.h>

// VQ forward on MI355X — round 2.
// x: [32768, 512] fp32, codebook: [8192, 512] fp32.
// d_out (float32): [16.7M) quantized_st | [1] vq_loss | [32768] indices-as-float
//
// R2 changes vs R1 (which passed, absmax 0, 6.7ms main kernel):
//  - 8x8 microtile, BM=BN=128: FMA:ds_read ratio 2x (LDS-throughput was the cap)
//  - permuted LDS layout [kk][part][g][4]: all frag reads & staging writes are
//    16B-stride -> only 2-way bank aliasing (free); kills the 8.7e8 conflict cycles
//    (old layout: 32B-stride frag reads + scalar staging = 4-way conflicts)
//  - codes split 4-way across blockIdx.y: 1024 blocks -> 4 blocks/CU, 16 waves/CU
//    (old grid of 512 blocks capped occupancy at 2 blocks/CU); per-quarter packed
//    argmin -> ws, merged in epilogue (no global atomics, no ws zero-init needed)
//  - k accumulation order unchanged (kt 0..31, kk 0..15 sequential) -> bit-identical
//    dots -> identical argmin vs R1.

#define NROWS 32768
#define KCODES 8192
#define DD 512

#define BM 128
#define BN 128
#define BK 16
#define QUARTERS 4
#define CODES_PER_Q (KCODES / QUARTERS)

// ---------------- sum of fp32 squares per row (fp64 accumulate, round to fp32)
__global__ __launch_bounds__(256) void sumsq_kernel(const float* __restrict__ in,
                                                    float* __restrict__ out,
                                                    int nrows) {
  const int wave = threadIdx.x >> 6;
  const int lane = threadIdx.x & 63;
  const int row = blockIdx.x * 4 + wave;
  if (row >= nrows) return;
  const float* p = in + (size_t)row * DD;
  double s = 0.0;
#pragma unroll
  for (int j = 0; j < DD / 64; ++j) {
    float v = p[j * 64 + lane];
    float sq = v * v;               // fp32 square first (matches ref flat*flat)
    s += (double)sq;
  }
  for (int off = 32; off > 0; off >>= 1) s += __shfl_down(s, off, 64);
  if (lane == 0) out[row] = (float)s;
}

// ---------------- main: fp32 GEMM + fused fp32-chain dist + per-quarter argmin
__global__ __launch_bounds__(256, 4) void vq_argmin_kernel(
    const float* __restrict__ x, const float* __restrict__ cb,
    const float* __restrict__ xsq, const float* __restrict__ csq,
    unsigned long long* __restrict__ partial_min) {
  // permuted layout: element (kk, r) lives at kk*128 + ((r>>2)&1)*64 + (r>>3)*4 + (r&3)
  // -> frag read for group g: float4 at kk*128 + g*4 (rows g*8..+3) and +64 (rows g*8+4..+7)
  //    B: 16 distinct addrs, 16B stride -> 2-way bank aliasing (free). A: 4 addrs, broadcast.
  // -> staging scalar writes: bank = ((r>>3)*4 + (r&3)) & 31; within a wave r=lane&127
  //    distinct, r and r^4 share a bank (2-way, free).
  __shared__ float As[BK * BM];                 // 8 KB
  __shared__ float Bs[BK * BN];                 // 8 KB
  __shared__ unsigned long long best[BM];       // packed (dist_bits<<32)|idx

  const int tid = threadIdx.x;
  const int row0 = blockIdx.x * BM;
  const int cq = blockIdx.y;
  const int cbase = cq * CODES_PER_Q;

  for (int i = tid; i < BM; i += 256) best[i] = ~0ULL;

  const int ty = tid >> 4;            // 0..15 -> rows ty*8 .. ty*8+7
  const int tx = tid & 15;            // 0..15 -> codes tx*8 .. tx*8+7

  // staging: thread covers tile-row sr, k-chunk sc..sc+7 (8 contiguous floats)
  const int sr = tid & 127;
  const int sc = (tid >> 7) * 8;
  const int sperm = ((sr >> 2) & 1) * 64 + (sr >> 3) * 4 + (sr & 3);

  float xs_r[8];
#pragma unroll
  for (int i = 0; i < 8; ++i) xs_r[i] = xsq[row0 + ty * 8 + i];

  __syncthreads();

  for (int ct = 0; ct < CODES_PER_Q / BN; ++ct) {
    const int c0 = cbase + ct * BN;
    float acc[8][8];
#pragma unroll
    for (int i = 0; i < 8; ++i)
#pragma unroll
      for (int j = 0; j < 8; ++j) acc[i][j] = 0.0f;

    for (int kt = 0; kt < DD / BK; ++kt) {
      const int kb = kt * BK;
      __syncthreads();   // previous iteration's readers done
      {
        const float* ap = x + (size_t)(row0 + sr) * DD + kb + sc;
        float4 av0 = *(const float4*)ap;
        float4 av1 = *(const float4*)(ap + 4);
        const float* bp = cb + (size_t)(c0 + sr) * DD + kb + sc;
        float4 bv0 = *(const float4*)bp;
        float4 bv1 = *(const float4*)(bp + 4);
        As[(sc + 0) * BM + sperm] = av0.x;
        As[(sc + 1) * BM + sperm] = av0.y;
        As[(sc + 2) * BM + sperm] = av0.z;
        As[(sc + 3) * BM + sperm] = av0.w;
        As[(sc + 4) * BM + sperm] = av1.x;
        As[(sc + 5) * BM + sperm] = av1.y;
        As[(sc + 6) * BM + sperm] = av1.z;
        As[(sc + 7) * BM + sperm] = av1.w;
        Bs[(sc + 0) * BN + sperm] = bv0.x;
        Bs[(sc + 1) * BN + sperm] = bv0.y;
        Bs[(sc + 2) * BN + sperm] = bv0.z;
        Bs[(sc + 3) * BN + sperm] = bv0.w;
        Bs[(sc + 4) * BN + sperm] = bv1.x;
        Bs[(sc + 5) * BN + sperm] = bv1.y;
        Bs[(sc + 6) * BN + sperm] = bv1.z;
        Bs[(sc + 7) * BN + sperm] = bv1.w;
      }
      __syncthreads();
#pragma unroll
      for (int kk = 0; kk < BK; ++kk) {
        float a[8], b[8];
        *(float4*)&a[0] = *(const float4*)&As[kk * BM + ty * 4];
        *(float4*)&a[4] = *(const float4*)&As[kk * BM + 64 + ty * 4];
        *(float4*)&b[0] = *(const float4*)&Bs[kk * BN + tx * 4];
        *(float4*)&b[4] = *(const float4*)&Bs[kk * BN + 64 + tx * 4];
#pragma unroll
        for (int i = 0; i < 8; ++i)
#pragma unroll
          for (int j = 0; j < 8; ++j) acc[i][j] = fmaf(a[i], b[j], acc[i][j]);
      }
    }

    // per-code-tile argmin epilogue, replicating ref fp32 rounding chain
    float cs[8];
#pragma unroll
    for (int j = 0; j < 8; ++j) cs[j] = csq[c0 + tx * 8 + j];
#pragma unroll
    for (int i = 0; i < 8; ++i) {
      float bd = 3.0e38f;
      int bj = 0;
#pragma unroll
      for (int j = 0; j < 8; ++j) {
        float t = xs_r[i] - 2.0f * acc[i][j];   // one rounding
        float d = t + cs[j];                    // one rounding (magnitude ~512)
        if (d < bd) { bd = d; bj = j; }         // strict < keeps lowest j on tie
      }
      unsigned long long pk =
          ((unsigned long long)__float_as_uint(bd) << 32) |
          (unsigned)(c0 + tx * 8 + bj);
      atomicMin(&best[ty * 8 + i], pk);
    }
  }
  __syncthreads();
  if (tid < BM)
    partial_min[(size_t)(row0 + tid) * QUARTERS + cq] = best[tid];
}

// ---------------- merge quarters + gather + straight-through + loss partial
__global__ __launch_bounds__(128) void epilogue_kernel(
    const float* __restrict__ x, const float* __restrict__ cb,
    const unsigned long long* __restrict__ partial_min,
    float* __restrict__ out_q, float* __restrict__ out_idx_f,
    double* __restrict__ partials) {
  const int row = blockIdx.x;
  const int t = threadIdx.x;
  __shared__ int ksh;
  if (t == 0) {
    unsigned long long m = partial_min[(size_t)row * QUARTERS];
#pragma unroll
    for (int q = 1; q < QUARTERS; ++q) {
      unsigned long long v = partial_min[(size_t)row * QUARTERS + q];
      if (v < m) m = v;   // packed: equal dist bits -> lower idx wins (numpy tie-break)
    }
    ksh = (int)(m & 0xffffffffu);
  }
  __syncthreads();
  const int k = ksh;

  const float4* xr = (const float4*)(x + (size_t)row * DD);
  const float4* qr = (const float4*)(cb + (size_t)k * DD);
  float4* orow = (float4*)(out_q + (size_t)row * DD);

  float4 xv = xr[t];
  float4 qv = qr[t];
  float dx = qv.x - xv.x, dy = qv.y - xv.y, dz = qv.z - xv.z, dw = qv.w - xv.w;
  float4 o;
  o.x = xv.x + dx; o.y = xv.y + dy; o.z = xv.z + dz; o.w = xv.w + dw;
  orow[t] = o;

  float s0 = dx * dx, s1 = dy * dy, s2 = dz * dz, s3 = dw * dw;  // fp32 squares
  double part = (double)s0 + (double)s1 + (double)s2 + (double)s3;

  for (int off = 32; off > 0; off >>= 1) part += __shfl_down(part, off, 64);
  __shared__ double red[2];
  const int lane = t & 63, wv = t >> 6;
  if (lane == 0) red[wv] = part;
  __syncthreads();
  if (t == 0) {
    partials[row] = red[0] + red[1];
    out_idx_f[row] = (float)k;
  }
}

// ---------------- reduce partials -> vq_loss
__global__ __launch_bounds__(256) void finalize_kernel(
    const double* __restrict__ partials, float* __restrict__ out_loss) {
  __shared__ double red[256];
  double s = 0.0;
  for (int i = threadIdx.x; i < NROWS; i += 256) s += partials[i];
  red[threadIdx.x] = s;
  __syncthreads();
  for (int st = 128; st > 0; st >>= 1) {
    if (threadIdx.x < st) red[threadIdx.x] += red[threadIdx.x + st];
    __syncthreads();
  }
  if (threadIdx.x == 0) {
    double mean = red[0] / ((double)NROWS * (double)DD);
    float cl = (float)mean;                // codebook_loss == commitment_loss
    out_loss[0] = cl + 0.25f * cl;         // fl(cl + fl(0.25*cl)), matches ref
  }
}

extern "C" void kernel_launch(void* const* d_in, const int* in_sizes, int n_in,
                              void* d_out, int out_size, void* d_ws,
                              size_t ws_size, hipStream_t stream) {
  const float* x = (const float*)d_in[0];
  const float* cb = (const float*)d_in[1];
  float* out = (float*)d_out;

  // ws layout (every slot fully rewritten each launch; no zero-init needed):
  char* ws = (char*)d_ws;
  double* partials = (double*)ws;                                   // 262144 B
  unsigned long long* partial_min = (unsigned long long*)(ws + 262144);  // 32768*4*8 = 1048576 B
  float* csq = (float*)(ws + 262144 + 1048576);                     //  32768 B
  float* xsq = (float*)(ws + 262144 + 1048576 + 32768);             // 131072 B

  sumsq_kernel<<<KCODES / 4, 256, 0, stream>>>(cb, csq, KCODES);
  sumsq_kernel<<<NROWS / 4, 256, 0, stream>>>(x, xsq, NROWS);
  dim3 grid(NROWS / BM, QUARTERS);
  vq_argmin_kernel<<<grid, 256, 0, stream>>>(x, cb, xsq, csq, partial_min);
  epilogue_kernel<<<NROWS, 128, 0, stream>>>(x, cb, partial_min, out,
                                             out + 16777216 + 1, partials);
  finalize_kernel<<<1, 256, 0, stream>>>(partials, out + 16777216);
}

// Round 3
// 4566.470 us; speedup vs baseline: 1.2660x; 1.2660x over previous
//
#include <hip/hip_runtime.h>

// VQ forward on MI355X — round 3.
// x: [32768, 512] fp32, codebook: [8192, 512] fp32.
// d_out (float32): [16.7M) quantized_st | [1] vq_loss | [32768] indices-as-float
//
// R3 change vs R2: __launch_bounds__(256, 2) on the main kernel (was (256,4)).
// R2's (256,4) capped the allocator at 128 VGPRs; it allocated 64 and SPILLED
// the 8x8 accumulator tile to scratch (evidence: WRITE_SIZE 800 MB for a kernel
// that stores ~1 MB, FETCH +0.8 GB, VALUBusy 61% with only 26% of cycles worth
// of FMA). (256,2) caps at 256 VGPRs; the tile needs ~110-130 -> no spill.
// Everything else (permuted conflict-free LDS layout, 4-way code split,
// bit-exact k-order fp32 chain) is identical to R2, which passed absmax 0.

#define NROWS 32768
#define KCODES 8192
#define DD 512

#define BM 128
#define BN 128
#define BK 16
#define QUARTERS 4
#define CODES_PER_Q (KCODES / QUARTERS)

// ---------------- sum of fp32 squares per row (fp64 accumulate, round to fp32)
__global__ __launch_bounds__(256) void sumsq_kernel(const float* __restrict__ in,
                                                    float* __restrict__ out,
                                                    int nrows) {
  const int wave = threadIdx.x >> 6;
  const int lane = threadIdx.x & 63;
  const int row = blockIdx.x * 4 + wave;
  if (row >= nrows) return;
  const float* p = in + (size_t)row * DD;
  double s = 0.0;
#pragma unroll
  for (int j = 0; j < DD / 64; ++j) {
    float v = p[j * 64 + lane];
    float sq = v * v;               // fp32 square first (matches ref flat*flat)
    s += (double)sq;
  }
  for (int off = 32; off > 0; off >>= 1) s += __shfl_down(s, off, 64);
  if (lane == 0) out[row] = (float)s;
}

// ---------------- main: fp32 GEMM + fused fp32-chain dist + per-quarter argmin
__global__ __launch_bounds__(256, 2) void vq_argmin_kernel(
    const float* __restrict__ x, const float* __restrict__ cb,
    const float* __restrict__ xsq, const float* __restrict__ csq,
    unsigned long long* __restrict__ partial_min) {
  // permuted layout: element (kk, r) lives at kk*128 + ((r>>2)&1)*64 + (r>>3)*4 + (r&3)
  // -> frag read for group g: float4 at kk*128 + g*4 (rows g*8..+3) and +64 (rows g*8+4..+7)
  //    B: 16 distinct addrs, 16B stride -> 2-way bank aliasing (free). A: 4 addrs, broadcast.
  // -> staging scalar writes: bank = ((r>>3)*4 + (r&3)) & 31; r and r^4 share a
  //    bank (2-way, free), otherwise distinct.
  __shared__ float As[BK * BM];                 // 8 KB
  __shared__ float Bs[BK * BN];                 // 8 KB
  __shared__ unsigned long long best[BM];       // packed (dist_bits<<32)|idx

  const int tid = threadIdx.x;
  const int row0 = blockIdx.x * BM;
  const int cq = blockIdx.y;
  const int cbase = cq * CODES_PER_Q;

  for (int i = tid; i < BM; i += 256) best[i] = ~0ULL;

  const int ty = tid >> 4;            // 0..15 -> rows ty*8 .. ty*8+7
  const int tx = tid & 15;            // 0..15 -> codes tx*8 .. tx*8+7

  // staging: thread covers tile-row sr, k-chunk sc..sc+7 (8 contiguous floats)
  const int sr = tid & 127;
  const int sc = (tid >> 7) * 8;
  const int sperm = ((sr >> 2) & 1) * 64 + (sr >> 3) * 4 + (sr & 3);

  float xs_r[8];
#pragma unroll
  for (int i = 0; i < 8; ++i) xs_r[i] = xsq[row0 + ty * 8 + i];

  __syncthreads();

  for (int ct = 0; ct < CODES_PER_Q / BN; ++ct) {
    const int c0 = cbase + ct * BN;
    float acc[8][8];
#pragma unroll
    for (int i = 0; i < 8; ++i)
#pragma unroll
      for (int j = 0; j < 8; ++j) acc[i][j] = 0.0f;

    for (int kt = 0; kt < DD / BK; ++kt) {
      const int kb = kt * BK;
      __syncthreads();   // previous iteration's readers done
      {
        const float* ap = x + (size_t)(row0 + sr) * DD + kb + sc;
        float4 av0 = *(const float4*)ap;
        float4 av1 = *(const float4*)(ap + 4);
        const float* bp = cb + (size_t)(c0 + sr) * DD + kb + sc;
        float4 bv0 = *(const float4*)bp;
        float4 bv1 = *(const float4*)(bp + 4);
        As[(sc + 0) * BM + sperm] = av0.x;
        As[(sc + 1) * BM + sperm] = av0.y;
        As[(sc + 2) * BM + sperm] = av0.z;
        As[(sc + 3) * BM + sperm] = av0.w;
        As[(sc + 4) * BM + sperm] = av1.x;
        As[(sc + 5) * BM + sperm] = av1.y;
        As[(sc + 6) * BM + sperm] = av1.z;
        As[(sc + 7) * BM + sperm] = av1.w;
        Bs[(sc + 0) * BN + sperm] = bv0.x;
        Bs[(sc + 1) * BN + sperm] = bv0.y;
        Bs[(sc + 2) * BN + sperm] = bv0.z;
        Bs[(sc + 3) * BN + sperm] = bv0.w;
        Bs[(sc + 4) * BN + sperm] = bv1.x;
        Bs[(sc + 5) * BN + sperm] = bv1.y;
        Bs[(sc + 6) * BN + sperm] = bv1.z;
        Bs[(sc + 7) * BN + sperm] = bv1.w;
      }
      __syncthreads();
#pragma unroll
      for (int kk = 0; kk < BK; ++kk) {
        float a[8], b[8];
        *(float4*)&a[0] = *(const float4*)&As[kk * BM + ty * 4];
        *(float4*)&a[4] = *(const float4*)&As[kk * BM + 64 + ty * 4];
        *(float4*)&b[0] = *(const float4*)&Bs[kk * BN + tx * 4];
        *(float4*)&b[4] = *(const float4*)&Bs[kk * BN + 64 + tx * 4];
#pragma unroll
        for (int i = 0; i < 8; ++i)
#pragma unroll
          for (int j = 0; j < 8; ++j) acc[i][j] = fmaf(a[i], b[j], acc[i][j]);
      }
    }

    // per-code-tile argmin epilogue, replicating ref fp32 rounding chain
    float cs[8];
#pragma unroll
    for (int j = 0; j < 8; ++j) cs[j] = csq[c0 + tx * 8 + j];
#pragma unroll
    for (int i = 0; i < 8; ++i) {
      float bd = 3.0e38f;
      int bj = 0;
#pragma unroll
      for (int j = 0; j < 8; ++j) {
        float t = xs_r[i] - 2.0f * acc[i][j];   // one rounding
        float d = t + cs[j];                    // one rounding (magnitude ~512)
        if (d < bd) { bd = d; bj = j; }         // strict < keeps lowest j on tie
      }
      unsigned long long pk =
          ((unsigned long long)__float_as_uint(bd) << 32) |
          (unsigned)(c0 + tx * 8 + bj);
      atomicMin(&best[ty * 8 + i], pk);
    }
  }
  __syncthreads();
  if (tid < BM)
    partial_min[(size_t)(row0 + tid) * QUARTERS + cq] = best[tid];
}

// ---------------- merge quarters + gather + straight-through + loss partial
__global__ __launch_bounds__(128) void epilogue_kernel(
    const float* __restrict__ x, const float* __restrict__ cb,
    const unsigned long long* __restrict__ partial_min,
    float* __restrict__ out_q, float* __restrict__ out_idx_f,
    double* __restrict__ partials) {
  const int row = blockIdx.x;
  const int t = threadIdx.x;
  __shared__ int ksh;
  if (t == 0) {
    unsigned long long m = partial_min[(size_t)row * QUARTERS];
#pragma unroll
    for (int q = 1; q < QUARTERS; ++q) {
      unsigned long long v = partial_min[(size_t)row * QUARTERS + q];
      if (v < m) m = v;   // packed: equal dist bits -> lower idx wins (numpy tie-break)
    }
    ksh = (int)(m & 0xffffffffu);
  }
  __syncthreads();
  const int k = ksh;

  const float4* xr = (const float4*)(x + (size_t)row * DD);
  const float4* qr = (const float4*)(cb + (size_t)k * DD);
  float4* orow = (float4*)(out_q + (size_t)row * DD);

  float4 xv = xr[t];
  float4 qv = qr[t];
  float dx = qv.x - xv.x, dy = qv.y - xv.y, dz = qv.z - xv.z, dw = qv.w - xv.w;
  float4 o;
  o.x = xv.x + dx; o.y = xv.y + dy; o.z = xv.z + dz; o.w = xv.w + dw;
  orow[t] = o;

  float s0 = dx * dx, s1 = dy * dy, s2 = dz * dz, s3 = dw * dw;  // fp32 squares
  double part = (double)s0 + (double)s1 + (double)s2 + (double)s3;

  for (int off = 32; off > 0; off >>= 1) part += __shfl_down(part, off, 64);
  __shared__ double red[2];
  const int lane = t & 63, wv = t >> 6;
  if (lane == 0) red[wv] = part;
  __syncthreads();
  if (t == 0) {
    partials[row] = red[0] + red[1];
    out_idx_f[row] = (float)k;
  }
}

// ---------------- reduce partials -> vq_loss
__global__ __launch_bounds__(256) void finalize_kernel(
    const double* __restrict__ partials, float* __restrict__ out_loss) {
  __shared__ double red[256];
  double s = 0.0;
  for (int i = threadIdx.x; i < NROWS; i += 256) s += partials[i];
  red[threadIdx.x] = s;
  __syncthreads();
  for (int st = 128; st > 0; st >>= 1) {
    if (threadIdx.x < st) red[threadIdx.x] += red[threadIdx.x + st];
    __syncthreads();
  }
  if (threadIdx.x == 0) {
    double mean = red[0] / ((double)NROWS * (double)DD);
    float cl = (float)mean;                // codebook_loss == commitment_loss
    out_loss[0] = cl + 0.25f * cl;         // fl(cl + fl(0.25*cl)), matches ref
  }
}

extern "C" void kernel_launch(void* const* d_in, const int* in_sizes, int n_in,
                              void* d_out, int out_size, void* d_ws,
                              size_t ws_size, hipStream_t stream) {
  const float* x = (const float*)d_in[0];
  const float* cb = (const float*)d_in[1];
  float* out = (float*)d_out;

  // ws layout (every slot fully rewritten each launch; no zero-init needed):
  char* ws = (char*)d_ws;
  double* partials = (double*)ws;                                   // 262144 B
  unsigned long long* partial_min = (unsigned long long*)(ws + 262144);  // 32768*4*8 = 1048576 B
  float* csq = (float*)(ws + 262144 + 1048576);                     //  32768 B
  float* xsq = (float*)(ws + 262144 + 1048576 + 32768);             // 131072 B

  sumsq_kernel<<<KCODES / 4, 256, 0, stream>>>(cb, csq, KCODES);
  sumsq_kernel<<<NROWS / 4, 256, 0, stream>>>(x, xsq, NROWS);
  dim3 grid(NROWS / BM, QUARTERS);
  vq_argmin_kernel<<<grid, 256, 0, stream>>>(x, cb, xsq, csq, partial_min);
  epilogue_kernel<<<NROWS, 128, 0, stream>>>(x, cb, partial_min, out,
                                             out + 16777216 + 1, partials);
  finalize_kernel<<<1, 256, 0, stream>>>(partials, out + 16777216);
}

// Round 4
// 4479.194 us; speedup vs baseline: 1.2907x; 1.0195x over previous
//
#include <hip/hip_runtime.h>

// VQ forward on MI355X — round 4.
// x: [32768, 512] fp32, codebook: [8192, 512] fp32.
// d_out (float32): [16.7M) quantized_st | [1] vq_loss | [32768] indices-as-float
//
// R4 changes vs R3 (passed, absmax 0, main kernel 5.4ms rocprof):
//  - __launch_bounds__(256, 1): R3's (256,2) left VGPR_Count=88 — too few for the
//    64-reg 8x8 accumulator -> compiler parked accs in AGPRs, and v_fmac_f32 can't
//    address AGPRs (ISA: VALU srcs are vN only) -> accvgpr_read/write around FMAs
//    = the ~2.3ms of phantom VALU issue (75% busy x 5.4ms vs 1.75ms pure FMA).
//    (256,1) gives a 512-reg budget; tile fits in arch VGPRs with room to spare.
//  - per-thread running argmin in registers instead of per-code-tile LDS atomicMin
//    (16 lanes hit the SAME best[] address per tile -> 512 serialized LDS atomics
//    per wave-tile). min is associative; packed tie-break unchanged. One shfl_xor
//    reduction over the 16 tx-lanes + one global write per row at the end.
//  - math chain (k-order, fp32 dist rounding) bit-identical to R1-R3.

#define NROWS 32768
#define KCODES 8192
#define DD 512

#define BM 128
#define BN 128
#define BK 16
#define QUARTERS 4
#define CODES_PER_Q (KCODES / QUARTERS)

// ---------------- sum of fp32 squares per row (fp64 accumulate, round to fp32)
__global__ __launch_bounds__(256) void sumsq_kernel(const float* __restrict__ in,
                                                    float* __restrict__ out,
                                                    int nrows) {
  const int wave = threadIdx.x >> 6;
  const int lane = threadIdx.x & 63;
  const int row = blockIdx.x * 4 + wave;
  if (row >= nrows) return;
  const float* p = in + (size_t)row * DD;
  double s = 0.0;
#pragma unroll
  for (int j = 0; j < DD / 64; ++j) {
    float v = p[j * 64 + lane];
    float sq = v * v;               // fp32 square first (matches ref flat*flat)
    s += (double)sq;
  }
  for (int off = 32; off > 0; off >>= 1) s += __shfl_down(s, off, 64);
  if (lane == 0) out[row] = (float)s;
}

// ---------------- main: fp32 GEMM + fused fp32-chain dist + per-quarter argmin
__global__ __launch_bounds__(256, 1) void vq_argmin_kernel(
    const float* __restrict__ x, const float* __restrict__ cb,
    const float* __restrict__ xsq, const float* __restrict__ csq,
    unsigned long long* __restrict__ partial_min) {
  // permuted layout: element (kk, r) lives at kk*128 + ((r>>2)&1)*64 + (r>>3)*4 + (r&3)
  // -> frag reads are float4 with broadcast across lanes (A: 4 uniq addrs/wave,
  //    B: 16 uniq, 16B stride -> 2-way bank aliasing, free)
  // -> staging scalar writes: bank = ((r>>3)*4 + (r&3)) & 31; r and r^4 share a
  //    bank (2-way, free), otherwise distinct.
  __shared__ float As[BK * BM];                 // 8 KB
  __shared__ float Bs[BK * BN];                 // 8 KB

  const int tid = threadIdx.x;
  const int row0 = blockIdx.x * BM;
  const int cq = blockIdx.y;
  const int cbase = cq * CODES_PER_Q;

  const int ty = tid >> 4;            // 0..15 -> rows ty*8 .. ty*8+7
  const int tx = tid & 15;            // 0..15 -> codes tx*8 .. tx*8+7

  // staging: thread covers tile-row sr, k-chunk sc..sc+7 (8 contiguous floats)
  const int sr = tid & 127;
  const int sc = (tid >> 7) * 8;
  const int sperm = ((sr >> 2) & 1) * 64 + (sr >> 3) * 4 + (sr & 3);

  float xs_r[8];
#pragma unroll
  for (int i = 0; i < 8; ++i) xs_r[i] = xsq[row0 + ty * 8 + i];

  // running per-(row i) packed argmin across all code tiles, in registers
  unsigned long long bestpk[8];
#pragma unroll
  for (int i = 0; i < 8; ++i) bestpk[i] = ~0ULL;

  for (int ct = 0; ct < CODES_PER_Q / BN; ++ct) {
    const int c0 = cbase + ct * BN;
    float acc[8][8];
#pragma unroll
    for (int i = 0; i < 8; ++i)
#pragma unroll
      for (int j = 0; j < 8; ++j) acc[i][j] = 0.0f;

    for (int kt = 0; kt < DD / BK; ++kt) {
      const int kb = kt * BK;
      __syncthreads();   // previous iteration's readers done
      {
        const float* ap = x + (size_t)(row0 + sr) * DD + kb + sc;
        float4 av0 = *(const float4*)ap;
        float4 av1 = *(const float4*)(ap + 4);
        const float* bp = cb + (size_t)(c0 + sr) * DD + kb + sc;
        float4 bv0 = *(const float4*)bp;
        float4 bv1 = *(const float4*)(bp + 4);
        As[(sc + 0) * BM + sperm] = av0.x;
        As[(sc + 1) * BM + sperm] = av0.y;
        As[(sc + 2) * BM + sperm] = av0.z;
        As[(sc + 3) * BM + sperm] = av0.w;
        As[(sc + 4) * BM + sperm] = av1.x;
        As[(sc + 5) * BM + sperm] = av1.y;
        As[(sc + 6) * BM + sperm] = av1.z;
        As[(sc + 7) * BM + sperm] = av1.w;
        Bs[(sc + 0) * BN + sperm] = bv0.x;
        Bs[(sc + 1) * BN + sperm] = bv0.y;
        Bs[(sc + 2) * BN + sperm] = bv0.z;
        Bs[(sc + 3) * BN + sperm] = bv0.w;
        Bs[(sc + 4) * BN + sperm] = bv1.x;
        Bs[(sc + 5) * BN + sperm] = bv1.y;
        Bs[(sc + 6) * BN + sperm] = bv1.z;
        Bs[(sc + 7) * BN + sperm] = bv1.w;
      }
      __syncthreads();
#pragma unroll
      for (int kk = 0; kk < BK; ++kk) {
        float a[8], b[8];
        *(float4*)&a[0] = *(const float4*)&As[kk * BM + ty * 4];
        *(float4*)&a[4] = *(const float4*)&As[kk * BM + 64 + ty * 4];
        *(float4*)&b[0] = *(const float4*)&Bs[kk * BN + tx * 4];
        *(float4*)&b[4] = *(const float4*)&Bs[kk * BN + 64 + tx * 4];
#pragma unroll
        for (int i = 0; i < 8; ++i)
#pragma unroll
          for (int j = 0; j < 8; ++j) acc[i][j] = fmaf(a[i], b[j], acc[i][j]);
      }
    }

    // per-code-tile argmin epilogue, replicating ref fp32 rounding chain
    float cs[8];
#pragma unroll
    for (int j = 0; j < 8; ++j) cs[j] = csq[c0 + tx * 8 + j];
#pragma unroll
    for (int i = 0; i < 8; ++i) {
      float bd = 3.0e38f;
      int bj = 0;
#pragma unroll
      for (int j = 0; j < 8; ++j) {
        float t = xs_r[i] - 2.0f * acc[i][j];   // one rounding
        float d = t + cs[j];                    // one rounding (magnitude ~512)
        if (d < bd) { bd = d; bj = j; }         // strict < keeps lowest j on tie
      }
      unsigned long long pk =
          ((unsigned long long)__float_as_uint(bd) << 32) |
          (unsigned)(c0 + tx * 8 + bj);
      if (pk < bestpk[i]) bestpk[i] = pk;       // associative min, order-free
    }
  }

  // reduce across the 16 tx-lanes sharing each row (lane bits 0..3 = tx)
#pragma unroll
  for (int i = 0; i < 8; ++i) {
    unsigned long long v = bestpk[i];
#pragma unroll
    for (int m = 8; m >= 1; m >>= 1) {
      unsigned long long o = __shfl_xor(v, m, 64);
      if (o < v) v = o;
    }
    if (tx == 0)
      partial_min[(size_t)(row0 + ty * 8 + i) * QUARTERS + cq] = v;
  }
}

// ---------------- merge quarters + gather + straight-through + loss partial
__global__ __launch_bounds__(128) void epilogue_kernel(
    const float* __restrict__ x, const float* __restrict__ cb,
    const unsigned long long* __restrict__ partial_min,
    float* __restrict__ out_q, float* __restrict__ out_idx_f,
    double* __restrict__ partials) {
  const int row = blockIdx.x;
  const int t = threadIdx.x;
  __shared__ int ksh;
  if (t == 0) {
    unsigned long long m = partial_min[(size_t)row * QUARTERS];
#pragma unroll
    for (int q = 1; q < QUARTERS; ++q) {
      unsigned long long v = partial_min[(size_t)row * QUARTERS + q];
      if (v < m) m = v;   // packed: equal dist bits -> lower idx wins (numpy tie-break)
    }
    ksh = (int)(m & 0xffffffffu);
  }
  __syncthreads();
  const int k = ksh;

  const float4* xr = (const float4*)(x + (size_t)row * DD);
  const float4* qr = (const float4*)(cb + (size_t)k * DD);
  float4* orow = (float4*)(out_q + (size_t)row * DD);

  float4 xv = xr[t];
  float4 qv = qr[t];
  float dx = qv.x - xv.x, dy = qv.y - xv.y, dz = qv.z - xv.z, dw = qv.w - xv.w;
  float4 o;
  o.x = xv.x + dx; o.y = xv.y + dy; o.z = xv.z + dz; o.w = xv.w + dw;
  orow[t] = o;

  float s0 = dx * dx, s1 = dy * dy, s2 = dz * dz, s3 = dw * dw;  // fp32 squares
  double part = (double)s0 + (double)s1 + (double)s2 + (double)s3;

  for (int off = 32; off > 0; off >>= 1) part += __shfl_down(part, off, 64);
  __shared__ double red[2];
  const int lane = t & 63, wv = t >> 6;
  if (lane == 0) red[wv] = part;
  __syncthreads();
  if (t == 0) {
    partials[row] = red[0] + red[1];
    out_idx_f[row] = (float)k;
  }
}

// ---------------- reduce partials -> vq_loss
__global__ __launch_bounds__(256) void finalize_kernel(
    const double* __restrict__ partials, float* __restrict__ out_loss) {
  __shared__ double red[256];
  double s = 0.0;
  for (int i = threadIdx.x; i < NROWS; i += 256) s += partials[i];
  red[threadIdx.x] = s;
  __syncthreads();
  for (int st = 128; st > 0; st >>= 1) {
    if (threadIdx.x < st) red[threadIdx.x] += red[threadIdx.x + st];
    __syncthreads();
  }
  if (threadIdx.x == 0) {
    double mean = red[0] / ((double)NROWS * (double)DD);
    float cl = (float)mean;                // codebook_loss == commitment_loss
    out_loss[0] = cl + 0.25f * cl;         // fl(cl + fl(0.25*cl)), matches ref
  }
}

extern "C" void kernel_launch(void* const* d_in, const int* in_sizes, int n_in,
                              void* d_out, int out_size, void* d_ws,
                              size_t ws_size, hipStream_t stream) {
  const float* x = (const float*)d_in[0];
  const float* cb = (const float*)d_in[1];
  float* out = (float*)d_out;

  // ws layout (every slot fully rewritten each launch; no zero-init needed):
  char* ws = (char*)d_ws;
  double* partials = (double*)ws;                                   // 262144 B
  unsigned long long* partial_min = (unsigned long long*)(ws + 262144);  // 32768*4*8 = 1048576 B
  float* csq = (float*)(ws + 262144 + 1048576);                     //  32768 B
  float* xsq = (float*)(ws + 262144 + 1048576 + 32768);             // 131072 B

  sumsq_kernel<<<KCODES / 4, 256, 0, stream>>>(cb, csq, KCODES);
  sumsq_kernel<<<NROWS / 4, 256, 0, stream>>>(x, xsq, NROWS);
  dim3 grid(NROWS / BM, QUARTERS);
  vq_argmin_kernel<<<grid, 256, 0, stream>>>(x, cb, xsq, csq, partial_min);
  epilogue_kernel<<<NROWS, 128, 0, stream>>>(x, cb, partial_min, out,
                                             out + 16777216 + 1, partials);
  finalize_kernel<<<1, 256, 0, stream>>>(partials, out + 16777216);
}

// Round 5
// 1638.214 us; speedup vs baseline: 3.5290x; 2.7342x over previous
//
#include <hip/hip_runtime.h>

// VQ forward on MI355X — round 5: MFMA coarse screen + exact fp32 rescore.
// x: [32768,512] fp32, codebook: [8192,512] fp32.
// d_out (fp32): [16.7M) quantized_st | [1] vq_loss | [32768] idx-as-float
//
// R4 post-mortem: VALU issued 2.3x the FMA content regardless of launch bounds
// (acc tile parked in AGPRs; v_fmac can't address aN). fp32-VALU floor is
// ~2.2ms anyway. R5 reroutes the 275-GFLOP distance GEMM through bf16 MFMA:
//  - phase 1 (coarse): x ~ xh+xm, cb ~ ch+cm (bf16 RNE splits); dot ~
//    hh+hm+mh chained into one fp32 MFMA acc. |err| <~1e-5 << MARGIN.
//    Per row keep codes with (csq - 2dot) <= runningMin + MARGIN -> ~4/row.
//  - phase 2 (rescore): candidates only, R1's bit-exact chain (sequential
//    fmaf k=0..511; t = xs - 2f*acc; d = t + cs; packed (dbits,idx) min ->
//    lowest index on ties). 2*acc is exact so fma-contraction is irrelevant.
//    Output == R1 (passed absmax 0) as long as candidates contain argmin:
//    argmin's coarse d is within (quantization 9e-5 + coarse-err 1e-5) of the
//    coarse min -> MARGIN 2.5e-4 has >2x slack. Overflow (>24 cands) -> full
//    8192-code exact scan for that row (P~0, safety only).
//  - cb bf16 splits precomputed into d_out[0..16.8MB) (scratch until the
//    epilogue overwrites d_out); x split on the fly during A staging.

#define NROWS 32768
#define KCODES 8192
#define DD 512
#define CAP 24
#define MARGIN 2.5e-4f

typedef __bf16 bf16_t;
typedef __bf16 bf16x4 __attribute__((ext_vector_type(4)));
typedef __bf16 bf16x8 __attribute__((ext_vector_type(8)));
typedef float f32x4 __attribute__((ext_vector_type(4)));

// LDS k-slot swizzle: slot s (8 bf16 = 16B) of row r lives at slot (s ^ ((r>>1)&3)).
// Frag reads (16 rows x quad-slot) -> 2-way bank alias only (free); 16B aligned.
#define SWZ(r, s) ((((s) ^ (((r) >> 1) & 3)) << 3))

// ---------------- sum of fp32 squares per row (fp64 accumulate, round to fp32)
__global__ __launch_bounds__(256) void sumsq_kernel(const float* __restrict__ in,
                                                    float* __restrict__ out,
                                                    int nrows) {
  const int wave = threadIdx.x >> 6;
  const int lane = threadIdx.x & 63;
  const int row = blockIdx.x * 4 + wave;
  if (row >= nrows) return;
  const float* p = in + (size_t)row * DD;
  double s = 0.0;
#pragma unroll
  for (int j = 0; j < DD / 64; ++j) {
    float v = p[j * 64 + lane];
    float sq = v * v;
    s += (double)sq;
  }
  for (int off = 32; off > 0; off >>= 1) s += __shfl_down(s, off, 64);
  if (lane == 0) out[row] = (float)s;
}

// ---------------- split codebook into bf16 hi/mid planes (in d_out scratch)
__global__ __launch_bounds__(256) void split_cb_kernel(const float* __restrict__ cb,
                                                       bf16_t* __restrict__ ch,
                                                       bf16_t* __restrict__ cm) {
  const int t = blockIdx.x * 256 + threadIdx.x;
  const int i = t * 4;  // 4.19M elems / 4
  float4 v = *(const float4*)(cb + i);
  bf16_t h0 = (bf16_t)v.x, h1 = (bf16_t)v.y, h2 = (bf16_t)v.z, h3 = (bf16_t)v.w;
  bf16_t m0 = (bf16_t)(v.x - (float)h0), m1 = (bf16_t)(v.y - (float)h1);
  bf16_t m2 = (bf16_t)(v.z - (float)h2), m3 = (bf16_t)(v.w - (float)h3);
  bf16x4 hv = {h0, h1, h2, h3};
  bf16x4 mv = {m0, m1, m2, m3};
  *(bf16x4*)(ch + i) = hv;
  *(bf16x4*)(cm + i) = mv;
}

// ---------------- phase 1: coarse MFMA GEMM + candidate screen
// grid (256 row-blocks, 2 code-halves) x 256 thr. Block tile 128 rows x 256
// codes per ct-iter; wave tile 64x128 (4x8 tiles of 16x16x32 bf16 mfma).
__global__ __launch_bounds__(256, 2) void coarse_kernel(
    const float* __restrict__ x, const bf16_t* __restrict__ cbh,
    const bf16_t* __restrict__ cbm, const float* __restrict__ csq,
    int* __restrict__ cnt, int* __restrict__ list) {
  __shared__ bf16_t As[2][128][32];   // 16 KB  [split][row][k]
  __shared__ bf16_t Bs[2][256][32];   // 32 KB
  __shared__ unsigned long long best[128];

  const int tid = threadIdx.x;
  const int wave = tid >> 6;
  const int lane = tid & 63;
  const int q = lane >> 4;
  const int l15 = lane & 15;
  const int rowOff = (wave & 1) * 64;
  const int colOff = (wave >> 1) * 128;
  const int row0 = blockIdx.x * 128;
  const int cbase = blockIdx.y * (KCODES / 2);

  for (int i = tid; i < 128; i += 256) best[i] = ~0ULL;
  __syncthreads();

  for (int ci = 0; ci < (KCODES / 2) / 256; ++ci) {
    const int c0 = cbase + ci * 256;
    f32x4 acc[4][8];
#pragma unroll
    for (int rt = 0; rt < 4; ++rt)
#pragma unroll
      for (int ct = 0; ct < 8; ++ct) {
        f32x4 z = {0.f, 0.f, 0.f, 0.f};
        acc[rt][ct] = z;
      }

    for (int kc = 0; kc < DD / 32; ++kc) {
      const int kb = kc * 32;
      __syncthreads();
      // ---- stage A (fp32 -> bf16 h/m on the fly): 1024 float4 / 256 thr
#pragma unroll
      for (int i = 0; i < 4; ++i) {
        const int f = i * 256 + tid;
        const int r = f >> 3;          // 0..127
        const int k4 = f & 7;          // float4 within the 32-k row
        float4 v = *(const float4*)(x + (size_t)(row0 + r) * DD + kb + k4 * 4);
        bf16_t h0 = (bf16_t)v.x, h1 = (bf16_t)v.y, h2 = (bf16_t)v.z, h3 = (bf16_t)v.w;
        bf16_t m0 = (bf16_t)(v.x - (float)h0), m1 = (bf16_t)(v.y - (float)h1);
        bf16_t m2 = (bf16_t)(v.z - (float)h2), m3 = (bf16_t)(v.w - (float)h3);
        const int base = SWZ(r, k4 >> 1) + (k4 & 1) * 4;
        bf16x4 hv = {h0, h1, h2, h3};
        bf16x4 mv = {m0, m1, m2, m3};
        *(bf16x4*)&As[0][r][base] = hv;
        *(bf16x4*)&As[1][r][base] = mv;
      }
      // ---- stage B (pre-split bf16): 2 spl x 1024 b128 / 256 thr
#pragma unroll
      for (int i = 0; i < 4; ++i) {
        const int f = i * 256 + tid;
        const int r = f >> 2;          // 0..255
        const int sl = f & 3;          // 8-bf16 slot
        bf16x8 vh = *(const bf16x8*)(cbh + (size_t)(c0 + r) * DD + kb + sl * 8);
        bf16x8 vm = *(const bf16x8*)(cbm + (size_t)(c0 + r) * DD + kb + sl * 8);
        *(bf16x8*)&Bs[0][r][SWZ(r, sl)] = vh;
        *(bf16x8*)&Bs[1][r][SWZ(r, sl)] = vm;
      }
      __syncthreads();
      // ---- fragments + mfma (hh + hm + mh chained into one fp32 acc)
      bf16x8 Ah[4], Am[4];
#pragma unroll
      for (int rt = 0; rt < 4; ++rt) {
        const int rr = rowOff + rt * 16 + l15;
        Ah[rt] = *(const bf16x8*)&As[0][rr][SWZ(rr, q)];
        Am[rt] = *(const bf16x8*)&As[1][rr][SWZ(rr, q)];
      }
#pragma unroll
      for (int ct = 0; ct < 8; ++ct) {
        const int cc = colOff + ct * 16 + l15;
        bf16x8 Bh = *(const bf16x8*)&Bs[0][cc][SWZ(cc, q)];
        bf16x8 Bm = *(const bf16x8*)&Bs[1][cc][SWZ(cc, q)];
#pragma unroll
        for (int rt = 0; rt < 4; ++rt) {
          acc[rt][ct] = __builtin_amdgcn_mfma_f32_16x16x32_bf16(Ah[rt], Bh, acc[rt][ct], 0, 0, 0);
          acc[rt][ct] = __builtin_amdgcn_mfma_f32_16x16x32_bf16(Ah[rt], Bm, acc[rt][ct], 0, 0, 0);
          acc[rt][ct] = __builtin_amdgcn_mfma_f32_16x16x32_bf16(Am[rt], Bh, acc[rt][ct], 0, 0, 0);
        }
      }
    }

    // ---- screen. d' = 1 + csq - 2*dot (positive -> float-bit packed order ok)
    float cs1[8];
#pragma unroll
    for (int ct = 0; ct < 8; ++ct) cs1[ct] = 1.0f + csq[c0 + colOff + ct * 16 + l15];

    // running-min update (C/D layout m89: col=lane&15, row=(lane>>4)*4+reg)
#pragma unroll
    for (int rt = 0; rt < 4; ++rt)
#pragma unroll
      for (int reg = 0; reg < 4; ++reg) {
        unsigned long long m = ~0ULL;
#pragma unroll
        for (int ct = 0; ct < 8; ++ct) {
          float d = fmaf(-2.0f, acc[rt][ct][reg], cs1[ct]);
          unsigned long long pk = ((unsigned long long)__float_as_uint(d) << 32) |
                                  (unsigned)(c0 + colOff + ct * 16 + l15);
          if (pk < m) m = pk;
        }
#pragma unroll
        for (int s = 1; s <= 8; s <<= 1) {
          unsigned long long o = __shfl_xor(m, s, 64);
          if (o < m) m = o;
        }
        if (l15 == 0)
          atomicMin(&best[rowOff + rt * 16 + q * 4 + reg], m);
      }
    __syncthreads();   // both col-waves' mins visible
    // append pass
#pragma unroll
    for (int rt = 0; rt < 4; ++rt)
#pragma unroll
      for (int reg = 0; reg < 4; ++reg) {
        const int rloc = rowOff + rt * 16 + q * 4 + reg;
        const float thr = __uint_as_float((unsigned)(best[rloc] >> 32)) + MARGIN;
        const int grow = row0 + rloc;
#pragma unroll
        for (int ct = 0; ct < 8; ++ct) {
          float d = fmaf(-2.0f, acc[rt][ct][reg], cs1[ct]);
          if (d <= thr) {
            int pos = atomicAdd(&cnt[grow], 1);
            if (pos < CAP) list[(size_t)grow * CAP + pos] = c0 + colOff + ct * 16 + l15;
          }
        }
      }
    // next ci's first __syncthreads separates append reads from new atomics
  }
}

// ---------------- phase 2: exact rescore of candidates (R1's bit-exact chain)
__global__ __launch_bounds__(256) void rescore_kernel(
    const float* __restrict__ x, const float* __restrict__ cb,
    const float* __restrict__ xsq, const float* __restrict__ csq,
    const int* __restrict__ list, const int* __restrict__ cnt,
    int* __restrict__ idxbuf) {
  const int row = blockIdx.x * 4 + (threadIdx.x >> 6);
  const int lane = threadIdx.x & 63;
  const int n = cnt[row];
  const float xs = xsq[row];
  const float4* xr4 = (const float4*)(x + (size_t)row * DD);
  unsigned long long bestv = ~0ULL;

  if (n >= 1 && n <= CAP) {
    if (lane < n) {
      const int idx = list[(size_t)row * CAP + lane];
      const float4* cr4 = (const float4*)(cb + (size_t)idx * DD);
      float acc = 0.0f;
      for (int k4 = 0; k4 < DD / 4; ++k4) {     // sequential k, ascending: R1 order
        float4 xv = xr4[k4];
        float4 cv = cr4[k4];
        acc = fmaf(xv.x, cv.x, acc);
        acc = fmaf(xv.y, cv.y, acc);
        acc = fmaf(xv.z, cv.z, acc);
        acc = fmaf(xv.w, cv.w, acc);
      }
      float t = xs - 2.0f * acc;                // 2*acc exact -> one rounding
      float d = t + csq[idx];                   // one rounding
      bestv = ((unsigned long long)__float_as_uint(d) << 32) | (unsigned)idx;
    }
  } else {
    // safety fallback: full exact scan (cnt overflow or zero)
    for (int idx = lane; idx < KCODES; idx += 64) {
      const float4* cr4 = (const float4*)(cb + (size_t)idx * DD);
      float acc = 0.0f;
      for (int k4 = 0; k4 < DD / 4; ++k4) {
        float4 xv = xr4[k4];
        float4 cv = cr4[k4];
        acc = fmaf(xv.x, cv.x, acc);
        acc = fmaf(xv.y, cv.y, acc);
        acc = fmaf(xv.z, cv.z, acc);
        acc = fmaf(xv.w, cv.w, acc);
      }
      float t = xs - 2.0f * acc;
      float d = t + csq[idx];
      unsigned long long pk = ((unsigned long long)__float_as_uint(d) << 32) | (unsigned)idx;
      if (pk < bestv) bestv = pk;
    }
  }
#pragma unroll
  for (int s = 1; s <= 32; s <<= 1) {
    unsigned long long o = __shfl_xor(bestv, s, 64);
    if (o < bestv) bestv = o;
  }
  if (lane == 0) idxbuf[row] = (int)(bestv & 0xffffffffu);
}

// ---------------- gather + straight-through + loss partial + idx-as-float
__global__ __launch_bounds__(128) void epilogue_kernel(
    const float* __restrict__ x, const float* __restrict__ cb,
    const int* __restrict__ idxbuf, float* __restrict__ out_q,
    float* __restrict__ out_idx_f, double* __restrict__ partials) {
  const int row = blockIdx.x;
  const int t = threadIdx.x;
  const int k = idxbuf[row];

  const float4* xr = (const float4*)(x + (size_t)row * DD);
  const float4* qr = (const float4*)(cb + (size_t)k * DD);
  float4* orow = (float4*)(out_q + (size_t)row * DD);

  float4 xv = xr[t];
  float4 qv = qr[t];
  float dx = qv.x - xv.x, dy = qv.y - xv.y, dz = qv.z - xv.z, dw = qv.w - xv.w;
  float4 o;
  o.x = xv.x + dx; o.y = xv.y + dy; o.z = xv.z + dz; o.w = xv.w + dw;
  orow[t] = o;

  float s0 = dx * dx, s1 = dy * dy, s2 = dz * dz, s3 = dw * dw;
  double part = (double)s0 + (double)s1 + (double)s2 + (double)s3;
  for (int off = 32; off > 0; off >>= 1) part += __shfl_down(part, off, 64);
  __shared__ double red[2];
  const int lane = t & 63, wv = t >> 6;
  if (lane == 0) red[wv] = part;
  __syncthreads();
  if (t == 0) {
    partials[row] = red[0] + red[1];
    out_idx_f[row] = (float)k;
  }
}

// ---------------- reduce partials -> vq_loss
__global__ __launch_bounds__(256) void finalize_kernel(
    const double* __restrict__ partials, float* __restrict__ out_loss) {
  __shared__ double red[256];
  double s = 0.0;
  for (int i = threadIdx.x; i < NROWS; i += 256) s += partials[i];
  red[threadIdx.x] = s;
  __syncthreads();
  for (int st = 128; st > 0; st >>= 1) {
    if (threadIdx.x < st) red[threadIdx.x] += red[threadIdx.x + st];
    __syncthreads();
  }
  if (threadIdx.x == 0) {
    double mean = red[0] / ((double)NROWS * (double)DD);
    float cl = (float)mean;
    out_loss[0] = cl + 0.25f * cl;
  }
}

extern "C" void kernel_launch(void* const* d_in, const int* in_sizes, int n_in,
                              void* d_out, int out_size, void* d_ws,
                              size_t ws_size, hipStream_t stream) {
  const float* x = (const float*)d_in[0];
  const float* cb = (const float*)d_in[1];
  float* out = (float*)d_out;

  // ws: partials | idxbuf | csq | xsq | cnt | list  (~3.9 MB)
  char* ws = (char*)d_ws;
  double* partials = (double*)ws;                          // 262144 B
  int* idxbuf = (int*)(ws + 262144);                       // 131072 B
  float* csq = (float*)(ws + 262144 + 131072);             //  32768 B
  float* xsq = (float*)(ws + 262144 + 131072 + 32768);     // 131072 B
  int* cnt = (int*)(ws + 262144 + 131072 + 32768 + 131072);        // 131072 B
  int* list = (int*)(ws + 262144 + 131072 + 32768 + 131072 + 131072);  // 32768*24*4 B

  // cb bf16 splits live in d_out scratch (overwritten by epilogue later)
  bf16_t* cbh = (bf16_t*)d_out;                 // 8192*512 bf16
  bf16_t* cbm = cbh + (size_t)KCODES * DD;

  hipMemsetAsync(cnt, 0, NROWS * sizeof(int), stream);
  sumsq_kernel<<<KCODES / 4, 256, 0, stream>>>(cb, csq, KCODES);
  sumsq_kernel<<<NROWS / 4, 256, 0, stream>>>(x, xsq, NROWS);
  split_cb_kernel<<<(KCODES * DD / 4) / 256, 256, 0, stream>>>(cb, cbh, cbm);
  dim3 grid(NROWS / 128, 2);
  coarse_kernel<<<grid, 256, 0, stream>>>(x, cbh, cbm, csq, cnt, list);
  rescore_kernel<<<NROWS / 4, 256, 0, stream>>>(x, cb, xsq, csq, list, cnt, idxbuf);
  epilogue_kernel<<<NROWS, 128, 0, stream>>>(x, cb, idxbuf, out,
                                             out + 16777216 + 1, partials);
  finalize_kernel<<<1, 256, 0, stream>>>(partials, out + 16777216);
}